// Round 11
// baseline (396.357 us; speedup 1.0000x reference)
//
#include <hip/hip_runtime.h>
#include <hip/hip_bf16.h>
#include <math.h>

#define HIDDEN 1024
#define BATCH 32
#define SRC_LEN 2048
#define NROWS (BATCH * SRC_LEN)   // 65536
#define NEG_BIG -10000000000.0f

typedef __attribute__((ext_vector_type(8))) short bf16x8;
typedef __attribute__((ext_vector_type(4))) float f32x4;
typedef __attribute__((ext_vector_type(4))) unsigned uint32x4;

static __device__ __forceinline__ unsigned short f2bf(float f) {
  unsigned u = __float_as_uint(f);
  u = u + 0x7fffu + ((u >> 16) & 1u);
  return (unsigned short)(u >> 16);
}

// single-instruction packed fp32->bf16 (RNE), gfx950
static __device__ __forceinline__ unsigned cvtpk(float lo, float hi) {
  unsigned r;
  asm("v_cvt_pk_bf16_f32 %0, %1, %2" : "=v"(r) : "v"(lo), "v"(hi));
  return r;
}

// async global->LDS, 16B per lane
static __device__ __forceinline__ void gload16(const void* g, void* l) {
  __builtin_amdgcn_global_load_lds(
      reinterpret_cast<const __attribute__((address_space(1))) unsigned*>(
          reinterpret_cast<unsigned long long>(g)),
      reinterpret_cast<__attribute__((address_space(3))) unsigned*>(
          reinterpret_cast<unsigned long long>(l)),
      16, 0, 0);
}

// ---------------------------------------------------------------------------
// Kernel 0: WT[n][h] = bf16(W_enc[h][n]) — one-time transpose+convert.
// ---------------------------------------------------------------------------
__global__ __launch_bounds__(256) void k_wt(
    const float* __restrict__ W, unsigned short* __restrict__ WT) {
  __shared__ float ts[64][65];
  const int hy = blockIdx.y * 64, nx = blockIdx.x * 64;
  const int tid = threadIdx.x;
#pragma unroll
  for (int i = 0; i < 16; ++i) {
    int idx = tid + i * 256, r = idx >> 6, c = idx & 63;
    ts[r][c] = W[(HIDDEN + hy + r) * HIDDEN + nx + c];
  }
  __syncthreads();
#pragma unroll
  for (int i = 0; i < 16; ++i) {
    int idx = tid + i * 256, rn = idx >> 6, ch = idx & 63;
    WT[(nx + rn) * HIDDEN + hy + ch] = f2bf(ts[ch][rn]);
  }
}

// ---------------------------------------------------------------------------
// Kernel 1a/1b: dec_proj (parallel partials + reduce)
// ---------------------------------------------------------------------------
__global__ __launch_bounds__(256) void k_dec_part(
    const float* __restrict__ dh, const float* __restrict__ W,
    float* __restrict__ decpart) {
  const int kl = threadIdx.x & 63;
  const int bq = threadIdx.x >> 6;
  const int k = blockIdx.x * 64 + kl;
  const int h0 = blockIdx.y * 64;
  __shared__ float dh_s[64][33];
#pragma unroll
  for (int i = 0; i < 8; ++i) {
    int idx = threadIdx.x + i * 256;
    int b = idx >> 6, hh = idx & 63;
    dh_s[hh][b] = dh[b * HIDDEN + h0 + hh];
  }
  __syncthreads();
  float acc[8] = {0.f, 0.f, 0.f, 0.f, 0.f, 0.f, 0.f, 0.f};
#pragma unroll
  for (int hh = 0; hh < 64; ++hh) {
    float w = W[(h0 + hh) * HIDDEN + k];
#pragma unroll
    for (int bb = 0; bb < 8; ++bb) acc[bb] += dh_s[hh][bq * 8 + bb] * w;
  }
#pragma unroll
  for (int bb = 0; bb < 8; ++bb)
    decpart[blockIdx.y * (BATCH * HIDDEN) + (bq * 8 + bb) * HIDDEN + k] = acc[bb];
}

__global__ __launch_bounds__(256) void k_dec_reduce(
    const float* __restrict__ decpart, const float* __restrict__ bias,
    float* __restrict__ out) {
  int e = blockIdx.x * 256 + threadIdx.x;
  float s = bias[e & (HIDDEN - 1)];
#pragma unroll
  for (int hc = 0; hc < 16; ++hc) s += decpart[hc * (BATCH * HIDDEN) + e];
  out[e] = s;
}

// ---------------------------------------------------------------------------
// Kernel 2 (dominant): MFMA bf16 GEMM fused with tanh + v_w dot.
// R7 structure (proven best), retiled 128x128 for 2 blocks/CU: BK=64,
// 4 waves (2m x 2n), dbuf LDS 66KB, one __syncthreads per K-step,
// {ISSUE -> MFMA cluster -> WRITE -> sync}. 16x16x32 MFMA (conflict-free
// frag pattern for 128B swizzled rows — R10 showed 32x32 conflicts 4-way).
// ---------------------------------------------------------------------------
#define BM 128
#define BN 128
#define BK 64
#define NT (HIDDEN / BK)   // 16
#define NQ (HIDDEN / BN)   // 8 col-blocks

__global__ __launch_bounds__(256, 2) void k_energy_mfma(
    const float* __restrict__ enc, const unsigned short* __restrict__ WT,
    const float* __restrict__ dec_proj, const float* __restrict__ v_w,
    float* __restrict__ part) {
  __shared__ unsigned short As[2][BM * BK];  // 2 x 16 KB, 128B rows, swizzled
  __shared__ unsigned short Bs[2][BN * BK];  // 2 x 16 KB
  __shared__ float red[2][BM];               // 1 KB   (total ~66 KB)

  const int tid = threadIdx.x;
  const int lane = tid & 63;
  const int wid = tid >> 6;    // 0..3
  const int wm = wid >> 1;     // 0..1  (row half of 128)
  const int wn = wid & 1;      // 0..1  (col half of 128)
  const int l16 = lane & 15;
  const int kg = lane >> 4;    // 0..3

  // XCD-aware bijective swizzle: nwg=4096 (%8==0), 512 per XCD chunk.
  // 8 consecutive l share row0 (A panel shared in XCD L2).
  const int bid = blockIdx.x;
  const int l = (bid & 7) * 512 + (bid >> 3);
  const int n0 = (l & 7) * BN;
  const int row0 = (l >> 3) * BM;
  const int b = row0 >> 11;

  f32x4 acc[4][4];
#pragma unroll
  for (int m = 0; m < 4; ++m)
#pragma unroll
    for (int n = 0; n < 4; ++n) acc[m][n] = (f32x4){0.f, 0.f, 0.f, 0.f};

  const float4* enc4 = (const float4*)enc;

  // A: thread covers row rbase (=tid>>1), half (tid&1) of its 64 h-vals.
  const int rbase = tid >> 1;
  const int hhalf = tid & 1;
  const float4* ea = enc4 + (size_t)(row0 + rbase) * 256 + hhalf * 8;
  const unsigned aswz = ((unsigned)(rbase & 7)) << 4;
  const unsigned awoff = (unsigned)rbase * 128;  // + chunk slot, swizzled below

  // B: inverse-swizzled global source for linear global_load_lds dest.
  // wave w, call i: LDS rows w*32 + i*8 + (lane>>3), slot lane&7.
  const char* wb = (const char*)WT +
                   (size_t)(n0 + wid * 32 + (lane >> 3)) * 2048 +
                   ((((unsigned)(lane & 7)) * 16) ^ (((unsigned)(lane >> 3)) << 4));
  const unsigned bldsoff = (unsigned)wid * 4096;

  float4 pa[8];

#define STAGE_ISSUE(tile, pdst)                                            \
  do {                                                                     \
    _Pragma("unroll") for (int j = 0; j < 8; ++j)                          \
        pa[j] = ea[(size_t)(tile) * 16 + j];                               \
    _Pragma("unroll") for (int i = 0; i < 4; ++i)                          \
        gload16(wb + (size_t)i * 16384 + (size_t)(tile) * 128,             \
                (char*)Bs[pdst] + bldsoff + i * 1024);                     \
  } while (0)

#define STAGE_WRITE(pdst)                                                  \
  do {                                                                     \
    _Pragma("unroll") for (int j = 0; j < 4; ++j) {                        \
      uint32x4 q;                                                          \
      q.x = cvtpk(pa[2 * j].x, pa[2 * j].y);                               \
      q.y = cvtpk(pa[2 * j].z, pa[2 * j].w);                               \
      q.z = cvtpk(pa[2 * j + 1].x, pa[2 * j + 1].y);                       \
      q.w = cvtpk(pa[2 * j + 1].z, pa[2 * j + 1].w);                       \
      unsigned slot = (unsigned)(hhalf * 4 + j);                           \
      *(uint32x4*)((char*)As[pdst] + awoff + ((slot * 16) ^ aswz)) = q;    \
    }                                                                      \
  } while (0)

#define MFMA_STEP(p)                                                       \
  do {                                                                     \
    _Pragma("unroll") for (int ks = 0; ks < 2; ++ks) {                     \
      bf16x8 af[4], bv[4];                                                 \
      const unsigned koff = (unsigned)(ks * 64 + kg * 16);                 \
      _Pragma("unroll") for (int m = 0; m < 4; ++m) {                      \
        int r = wm * 64 + m * 16 + l16;                                    \
        unsigned off = (unsigned)r * 128 +                                 \
                       (koff ^ (((unsigned)(r & 7)) << 4));                \
        af[m] = *(const bf16x8*)((const char*)As[p] + off);                \
      }                                                                    \
      _Pragma("unroll") for (int n = 0; n < 4; ++n) {                      \
        int c = wn * 64 + n * 16 + l16;                                    \
        unsigned off = (unsigned)c * 128 +                                 \
                       (koff ^ (((unsigned)(c & 7)) << 4));                \
        bv[n] = *(const bf16x8*)((const char*)Bs[p] + off);                \
      }                                                                    \
      __builtin_amdgcn_s_setprio(1);                                       \
      _Pragma("unroll") for (int m = 0; m < 4; ++m)                        \
          _Pragma("unroll") for (int n = 0; n < 4; ++n)                    \
              acc[m][n] = __builtin_amdgcn_mfma_f32_16x16x32_bf16(         \
                  af[m], bv[n], acc[m][n], 0, 0, 0);                       \
      __builtin_amdgcn_s_setprio(0);                                       \
    }                                                                      \
  } while (0)

#define STEP(tt, p)                                                        \
  do {                                                                     \
    if ((tt) + 1 < NT) STAGE_ISSUE((tt) + 1, (p) ^ 1);                     \
    MFMA_STEP(p);                                                          \
    if ((tt) + 1 < NT) STAGE_WRITE((p) ^ 1);                               \
    __syncthreads();                                                       \
  } while (0)

  // prologue: stage tile 0 into buffer 0
  STAGE_ISSUE(0, 0);
  STAGE_WRITE(0);
  __syncthreads();

  for (int t = 0; t < NT; t += 2) {
    STEP(t, 0);
    STEP(t + 1, 1);
  }

  // epilogue: tanh + v_w dot; C/D layout: col=l16, row=kg*4+reg
  float dv[4], vv[4];
#pragma unroll
  for (int n = 0; n < 4; ++n) {
    int kc = n0 + wn * 64 + n * 16 + l16;
    dv[n] = dec_proj[b * HIDDEN + kc];
    vv[n] = v_w[kc];
  }
#pragma unroll
  for (int m = 0; m < 4; ++m) {
#pragma unroll
    for (int r = 0; r < 4; ++r) {
      float p = 0.f;
#pragma unroll
      for (int n = 0; n < 4; ++n) {
        float x = dv[n] + acc[m][n][r];
        float t = 1.f - 2.f / (__expf(2.f * x) + 1.f);  // tanh, saturating
        p += t * vv[n];
      }
      p += __shfl_xor(p, 1);
      p += __shfl_xor(p, 2);
      p += __shfl_xor(p, 4);
      p += __shfl_xor(p, 8);
      if (l16 == 0) red[wn][wm * 64 + m * 16 + kg * 4 + r] = p;
    }
  }
  __syncthreads();
  if (tid < BM) {
    float s = red[0][tid] + red[1][tid];
    part[(size_t)(l & 7) * NROWS + row0 + tid] = s;
  }
#undef STAGE_ISSUE
#undef STAGE_WRITE
#undef MFMA_STEP
#undef STEP
}

// ---------------------------------------------------------------------------
// Kernel 3: sum 8 col-block partials + masked softmax. grid 32, block 256.
// ---------------------------------------------------------------------------
__global__ __launch_bounds__(256) void k_softmax(
    const float* __restrict__ part, const int* __restrict__ mask,
    float* __restrict__ out_w) {
  int b = blockIdx.x, tid = threadIdx.x;
  __shared__ float red[4], red2[4];
  float l[8];
  float m = -INFINITY;
#pragma unroll
  for (int j = 0; j < 8; ++j) {
    int s = tid + 256 * j;
    int row = b * SRC_LEN + s;
    float x = 0.f;
#pragma unroll
    for (int q = 0; q < 8; ++q) x += part[(size_t)q * NROWS + row];
    l[j] = (mask[row] == 0) ? NEG_BIG : x;
    m = fmaxf(m, l[j]);
  }
#pragma unroll
  for (int off = 32; off; off >>= 1) m = fmaxf(m, __shfl_xor(m, off));
  if ((tid & 63) == 0) red[tid >> 6] = m;
  __syncthreads();
  m = fmaxf(fmaxf(red[0], red[1]), fmaxf(red[2], red[3]));
  float sum = 0.f;
#pragma unroll
  for (int j = 0; j < 8; ++j) {
    l[j] = expf(l[j] - m);
    sum += l[j];
  }
#pragma unroll
  for (int off = 32; off; off >>= 1) sum += __shfl_xor(sum, off);
  if ((tid & 63) == 0) red2[tid >> 6] = sum;
  __syncthreads();
  sum = red2[0] + red2[1] + red2[2] + red2[3];
  float inv = 1.f / sum;
#pragma unroll
  for (int j = 0; j < 8; ++j) out_w[b * SRC_LEN + tid + 256 * j] = l[j] * inv;
}

// ---------------------------------------------------------------------------
// Kernel 4/5: context partials + reduce.
// ---------------------------------------------------------------------------
__global__ __launch_bounds__(256) void k_ctx_partial(
    const float* __restrict__ w, const float* __restrict__ enc,
    float* __restrict__ part) {
  int b = blockIdx.x, sg = blockIdx.y, tid = threadIdx.x;
  const float4* enc4 = (const float4*)enc;
  float4 acc = {0.f, 0.f, 0.f, 0.f};
  int s0 = sg * 128;
#pragma unroll 4
  for (int s = 0; s < 128; ++s) {
    float ws = w[b * SRC_LEN + s0 + s];
    float4 e = enc4[(size_t)(b * SRC_LEN + s0 + s) * 256 + tid];
    acc.x += ws * e.x;
    acc.y += ws * e.y;
    acc.z += ws * e.z;
    acc.w += ws * e.w;
  }
  ((float4*)part)[(b * 16 + sg) * 256 + tid] = acc;
}

__global__ __launch_bounds__(256) void k_ctx_reduce(
    const float* __restrict__ part, float* __restrict__ ctx) {
  int b = blockIdx.x, tid = threadIdx.x;
  float4 acc = {0.f, 0.f, 0.f, 0.f};
#pragma unroll
  for (int sg = 0; sg < 16; ++sg) {
    float4 p = ((const float4*)part)[(b * 16 + sg) * 256 + tid];
    acc.x += p.x;
    acc.y += p.y;
    acc.z += p.z;
    acc.w += p.w;
  }
  ((float4*)ctx)[b * 256 + tid] = acc;
}

// ---------------------------------------------------------------------------
extern "C" void kernel_launch(void* const* d_in, const int* in_sizes, int n_in,
                              void* d_out, int out_size, void* d_ws, size_t ws_size,
                              hipStream_t stream) {
  const float* dh = (const float*)d_in[0];
  const float* enc = (const float*)d_in[1];
  const int* mask = (const int*)d_in[2];
  const float* attn_W = (const float*)d_in[3];
  const float* attn_b = (const float*)d_in[4];
  const float* v_w = (const float*)d_in[5];

  float* out_w = (float*)d_out;                   // [32][2048]
  float* out_ctx = (float*)d_out + NROWS;         // [32][1024]

  // ws layout (floats). part aliases decpart: decpart's lifetime
  // (k_dec_part -> k_dec_reduce) ends before k_energy writes part.
  float* ws = (float*)d_ws;
  float* part = ws;                               // 8 * 65536 = 524288
  float* decpart = ws;                            // 16*32*1024 = 524288 (alias)
  float* dec_proj = ws + 8 * NROWS;               // 32768
  unsigned short* WT = (unsigned short*)(dec_proj + BATCH * HIDDEN);  // 1Mi bf16
  float* ctxpart = dec_proj + BATCH * HIDDEN + (HIDDEN * HIDDEN / 2); // 524288

  k_wt<<<dim3(16, 16), 256, 0, stream>>>(attn_W, WT);
  k_dec_part<<<dim3(16, 16), 256, 0, stream>>>(dh, attn_W, decpart);
  k_dec_reduce<<<dim3(128), 256, 0, stream>>>(decpart, attn_b, dec_proj);
  k_energy_mfma<<<dim3(4096), 256, 0, stream>>>(enc, WT, dec_proj, v_w, part);
  k_softmax<<<dim3(BATCH), 256, 0, stream>>>(part, mask, out_w);
  k_ctx_partial<<<dim3(BATCH, 16), 256, 0, stream>>>(out_w, enc, ctxpart);
  k_ctx_reduce<<<dim3(BATCH), 256, 0, stream>>>(ctxpart, out_ctx);
}

// Round 12
// 307.421 us; speedup vs baseline: 1.2893x; 1.2893x over previous
//
#include <hip/hip_runtime.h>
#include <hip/hip_bf16.h>
#include <math.h>

#define HIDDEN 1024
#define BATCH 32
#define SRC_LEN 2048
#define NROWS (BATCH * SRC_LEN)   // 65536
#define NEG_BIG -10000000000.0f

typedef __attribute__((ext_vector_type(8))) short bf16x8;
typedef __attribute__((ext_vector_type(4))) float f32x4;
typedef __attribute__((ext_vector_type(4))) unsigned uint32x4;

static __device__ __forceinline__ unsigned short f2bf(float f) {
  unsigned u = __float_as_uint(f);
  u = u + 0x7fffu + ((u >> 16) & 1u);
  return (unsigned short)(u >> 16);
}

// single-instruction packed fp32->bf16 (RNE), gfx950
static __device__ __forceinline__ unsigned cvtpk(float lo, float hi) {
  unsigned r;
  asm("v_cvt_pk_bf16_f32 %0, %1, %2" : "=v"(r) : "v"(lo), "v"(hi));
  return r;
}

// async global->LDS, 16B per lane
static __device__ __forceinline__ void gload16(const void* g, void* l) {
  __builtin_amdgcn_global_load_lds(
      reinterpret_cast<const __attribute__((address_space(1))) unsigned*>(
          reinterpret_cast<unsigned long long>(g)),
      reinterpret_cast<__attribute__((address_space(3))) unsigned*>(
          reinterpret_cast<unsigned long long>(l)),
      16, 0, 0);
}

// ---------------------------------------------------------------------------
// Kernel 0: WT[n][h] = bf16(W_enc[h][n]) — one-time transpose+convert.
// ---------------------------------------------------------------------------
__global__ __launch_bounds__(256) void k_wt(
    const float* __restrict__ W, unsigned short* __restrict__ WT) {
  __shared__ float ts[64][65];
  const int hy = blockIdx.y * 64, nx = blockIdx.x * 64;
  const int tid = threadIdx.x;
#pragma unroll
  for (int i = 0; i < 16; ++i) {
    int idx = tid + i * 256, r = idx >> 6, c = idx & 63;
    ts[r][c] = W[(HIDDEN + hy + r) * HIDDEN + nx + c];
  }
  __syncthreads();
#pragma unroll
  for (int i = 0; i < 16; ++i) {
    int idx = tid + i * 256, rn = idx >> 6, ch = idx & 63;
    WT[(nx + rn) * HIDDEN + hy + ch] = f2bf(ts[ch][rn]);
  }
}

// ---------------------------------------------------------------------------
// Kernel 1a/1b: dec_proj (parallel partials + reduce)
// ---------------------------------------------------------------------------
__global__ __launch_bounds__(256) void k_dec_part(
    const float* __restrict__ dh, const float* __restrict__ W,
    float* __restrict__ decpart) {
  const int kl = threadIdx.x & 63;
  const int bq = threadIdx.x >> 6;
  const int k = blockIdx.x * 64 + kl;
  const int h0 = blockIdx.y * 64;
  __shared__ float dh_s[64][33];
#pragma unroll
  for (int i = 0; i < 8; ++i) {
    int idx = threadIdx.x + i * 256;
    int b = idx >> 6, hh = idx & 63;
    dh_s[hh][b] = dh[b * HIDDEN + h0 + hh];
  }
  __syncthreads();
  float acc[8] = {0.f, 0.f, 0.f, 0.f, 0.f, 0.f, 0.f, 0.f};
#pragma unroll
  for (int hh = 0; hh < 64; ++hh) {
    float w = W[(h0 + hh) * HIDDEN + k];
#pragma unroll
    for (int bb = 0; bb < 8; ++bb) acc[bb] += dh_s[hh][bq * 8 + bb] * w;
  }
#pragma unroll
  for (int bb = 0; bb < 8; ++bb)
    decpart[blockIdx.y * (BATCH * HIDDEN) + (bq * 8 + bb) * HIDDEN + k] = acc[bb];
}

__global__ __launch_bounds__(256) void k_dec_reduce(
    const float* __restrict__ decpart, const float* __restrict__ bias,
    float* __restrict__ out) {
  int e = blockIdx.x * 256 + threadIdx.x;
  float s = bias[e & (HIDDEN - 1)];
#pragma unroll
  for (int hc = 0; hc < 16; ++hc) s += decpart[hc * (BATCH * HIDDEN) + e];
  out[e] = s;
}

// ---------------------------------------------------------------------------
// Kernel 2 (dominant): MFMA bf16 GEMM fused with tanh + v_w dot.
// R7 flow (proven best: {ISSUE -> MFMA -> WRITE -> __syncthreads}, dbuf),
// re-partitioned: 256(M) x 128(N) tile, BK=64, 1024 threads = 16 waves
// (4m x 4n, per-wave 64x32 out, acc[4][2]=32 AGPR) -> 4 waves/SIMD so
// ds_read waits of one wave hide under another's MFMAs. LDS 100 KB.
// ---------------------------------------------------------------------------
#define BM 256
#define BN 128
#define BK 64
#define NT (HIDDEN / BK)   // 16
#define NQ (HIDDEN / BN)   // 8 col-blocks

__global__ __launch_bounds__(1024, 4) void k_energy_mfma(
    const float* __restrict__ enc, const unsigned short* __restrict__ WT,
    const float* __restrict__ dec_proj, const float* __restrict__ v_w,
    float* __restrict__ part) {
  __shared__ unsigned short As[2][BM * BK];  // 2 x 32 KB, 128B rows, swizzled
  __shared__ unsigned short Bs[2][BN * BK];  // 2 x 16 KB
  __shared__ float red[4][BM];               // 4 KB   (total 100 KB)

  const int tid = threadIdx.x;
  const int lane = tid & 63;
  const int wid = tid >> 6;    // 0..15
  const int wm = wid >> 2;     // 0..3  (64-row group of 256)
  const int wn = wid & 3;      // 0..3  (32-col group of 128)
  const int l16 = lane & 15;
  const int kg = lane >> 4;    // 0..3

  // XCD-aware bijective swizzle: nwg=2048 (%8==0), 256 per XCD chunk.
  // consecutive l share row0's A panel within an XCD's L2.
  const int bid = blockIdx.x;
  const int l = (bid & 7) * 256 + (bid >> 3);
  const int n0 = (l & 7) * BN;
  const int row0 = (l >> 3) * BM;
  const int b = row0 >> 11;

  f32x4 acc[4][2];
#pragma unroll
  for (int m = 0; m < 4; ++m)
#pragma unroll
    for (int n = 0; n < 2; ++n) acc[m][n] = (f32x4){0.f, 0.f, 0.f, 0.f};

  const float4* enc4 = (const float4*)enc;

  // A: thread covers row rbase (=tid>>2), quarter q4 (=tid&3) of its 64 h.
  const int rbase = tid >> 2;
  const int q4 = tid & 3;
  const float4* ea = enc4 + (size_t)(row0 + rbase) * 256 + q4 * 4;
  const unsigned aswz = ((unsigned)(rbase & 7)) << 4;
  const unsigned awbase = (unsigned)rbase * 128;

  // B: inverse-swizzled global source for linear global_load_lds dest.
  // wave w covers LDS rows w*8 + (lane>>3), 16B slot lane&7 (one issue/tile).
  const char* wb = (const char*)WT +
                   (size_t)(n0 + wid * 8 + (lane >> 3)) * 2048 +
                   ((((unsigned)(lane & 7)) * 16) ^ (((unsigned)(lane >> 3)) << 4));
  const unsigned bldsoff = (unsigned)wid * 1024;

  float4 pa[4];

#define STAGE_ISSUE(tile, pdst)                                            \
  do {                                                                     \
    _Pragma("unroll") for (int j = 0; j < 4; ++j)                          \
        pa[j] = ea[(size_t)(tile) * 16 + j];                               \
    gload16(wb + (size_t)(tile) * 128, (char*)Bs[pdst] + bldsoff);         \
  } while (0)

#define STAGE_WRITE(pdst)                                                  \
  do {                                                                     \
    _Pragma("unroll") for (int j = 0; j < 2; ++j) {                        \
      uint32x4 qv;                                                         \
      qv.x = cvtpk(pa[2 * j].x, pa[2 * j].y);                              \
      qv.y = cvtpk(pa[2 * j].z, pa[2 * j].w);                              \
      qv.z = cvtpk(pa[2 * j + 1].x, pa[2 * j + 1].y);                      \
      qv.w = cvtpk(pa[2 * j + 1].z, pa[2 * j + 1].w);                      \
      unsigned slot = (unsigned)(q4 * 2 + j);                              \
      *(uint32x4*)((char*)As[pdst] + awbase + ((slot * 16) ^ aswz)) = qv;  \
    }                                                                      \
  } while (0)

#define MFMA_STEP(p)                                                       \
  do {                                                                     \
    _Pragma("unroll") for (int ks = 0; ks < 2; ++ks) {                     \
      bf16x8 af[4], bv[2];                                                 \
      const unsigned koff = (unsigned)(ks * 64 + kg * 16);                 \
      _Pragma("unroll") for (int m = 0; m < 4; ++m) {                      \
        int r = wm * 64 + m * 16 + l16;                                    \
        unsigned off = (unsigned)r * 128 +                                 \
                       (koff ^ (((unsigned)(r & 7)) << 4));                \
        af[m] = *(const bf16x8*)((const char*)As[p] + off);                \
      }                                                                    \
      _Pragma("unroll") for (int n = 0; n < 2; ++n) {                      \
        int c = wn * 32 + n * 16 + l16;                                    \
        unsigned off = (unsigned)c * 128 +                                 \
                       (koff ^ (((unsigned)(c & 7)) << 4));                \
        bv[n] = *(const bf16x8*)((const char*)Bs[p] + off);                \
      }                                                                    \
      __builtin_amdgcn_s_setprio(1);                                       \
      _Pragma("unroll") for (int m = 0; m < 4; ++m)                        \
          _Pragma("unroll") for (int n = 0; n < 2; ++n)                    \
              acc[m][n] = __builtin_amdgcn_mfma_f32_16x16x32_bf16(         \
                  af[m], bv[n], acc[m][n], 0, 0, 0);                       \
      __builtin_amdgcn_s_setprio(0);                                       \
    }                                                                      \
  } while (0)

#define STEP(tt, p)                                                        \
  do {                                                                     \
    if ((tt) + 1 < NT) STAGE_ISSUE((tt) + 1, (p) ^ 1);                     \
    MFMA_STEP(p);                                                          \
    if ((tt) + 1 < NT) STAGE_WRITE((p) ^ 1);                               \
    __syncthreads();                                                       \
  } while (0)

  // prologue: stage tile 0 into buffer 0
  STAGE_ISSUE(0, 0);
  STAGE_WRITE(0);
  __syncthreads();

  for (int t = 0; t < NT; t += 2) {
    STEP(t, 0);
    STEP(t + 1, 1);
  }

  // epilogue: tanh + v_w dot; C/D layout: col=l16, row=kg*4+reg
  float dv[2], vv[2];
#pragma unroll
  for (int n = 0; n < 2; ++n) {
    int kc = n0 + wn * 32 + n * 16 + l16;
    dv[n] = dec_proj[b * HIDDEN + kc];
    vv[n] = v_w[kc];
  }
#pragma unroll
  for (int m = 0; m < 4; ++m) {
#pragma unroll
    for (int r = 0; r < 4; ++r) {
      float p = 0.f;
#pragma unroll
      for (int n = 0; n < 2; ++n) {
        float x = dv[n] + acc[m][n][r];
        float t = 1.f - 2.f / (__expf(2.f * x) + 1.f);  // tanh, saturating
        p += t * vv[n];
      }
      p += __shfl_xor(p, 1);
      p += __shfl_xor(p, 2);
      p += __shfl_xor(p, 4);
      p += __shfl_xor(p, 8);
      if (l16 == 0) red[wn][wm * 64 + m * 16 + kg * 4 + r] = p;
    }
  }
  __syncthreads();
  if (tid < BM) {
    float s = red[0][tid] + red[1][tid] + red[2][tid] + red[3][tid];
    part[(size_t)(l & 7) * NROWS + row0 + tid] = s;
  }
#undef STAGE_ISSUE
#undef STAGE_WRITE
#undef MFMA_STEP
#undef STEP
}

// ---------------------------------------------------------------------------
// Kernel 3: sum 8 col-block partials + masked softmax. grid 32, block 256.
// ---------------------------------------------------------------------------
__global__ __launch_bounds__(256) void k_softmax(
    const float* __restrict__ part, const int* __restrict__ mask,
    float* __restrict__ out_w) {
  int b = blockIdx.x, tid = threadIdx.x;
  __shared__ float red[4], red2[4];
  float l[8];
  float m = -INFINITY;
#pragma unroll
  for (int j = 0; j < 8; ++j) {
    int s = tid + 256 * j;
    int row = b * SRC_LEN + s;
    float x = 0.f;
#pragma unroll
    for (int q = 0; q < 8; ++q) x += part[(size_t)q * NROWS + row];
    l[j] = (mask[row] == 0) ? NEG_BIG : x;
    m = fmaxf(m, l[j]);
  }
#pragma unroll
  for (int off = 32; off; off >>= 1) m = fmaxf(m, __shfl_xor(m, off));
  if ((tid & 63) == 0) red[tid >> 6] = m;
  __syncthreads();
  m = fmaxf(fmaxf(red[0], red[1]), fmaxf(red[2], red[3]));
  float sum = 0.f;
#pragma unroll
  for (int j = 0; j < 8; ++j) {
    l[j] = expf(l[j] - m);
    sum += l[j];
  }
#pragma unroll
  for (int off = 32; off; off >>= 1) sum += __shfl_xor(sum, off);
  if ((tid & 63) == 0) red2[tid >> 6] = sum;
  __syncthreads();
  sum = red2[0] + red2[1] + red2[2] + red2[3];
  float inv = 1.f / sum;
#pragma unroll
  for (int j = 0; j < 8; ++j) out_w[b * SRC_LEN + tid + 256 * j] = l[j] * inv;
}

// ---------------------------------------------------------------------------
// Kernel 4/5: context partials + reduce.
// ---------------------------------------------------------------------------
__global__ __launch_bounds__(256) void k_ctx_partial(
    const float* __restrict__ w, const float* __restrict__ enc,
    float* __restrict__ part) {
  int b = blockIdx.x, sg = blockIdx.y, tid = threadIdx.x;
  const float4* enc4 = (const float4*)enc;
  float4 acc = {0.f, 0.f, 0.f, 0.f};
  int s0 = sg * 128;
#pragma unroll 4
  for (int s = 0; s < 128; ++s) {
    float ws = w[b * SRC_LEN + s0 + s];
    float4 e = enc4[(size_t)(b * SRC_LEN + s0 + s) * 256 + tid];
    acc.x += ws * e.x;
    acc.y += ws * e.y;
    acc.z += ws * e.z;
    acc.w += ws * e.w;
  }
  ((float4*)part)[(b * 16 + sg) * 256 + tid] = acc;
}

__global__ __launch_bounds__(256) void k_ctx_reduce(
    const float* __restrict__ part, float* __restrict__ ctx) {
  int b = blockIdx.x, tid = threadIdx.x;
  float4 acc = {0.f, 0.f, 0.f, 0.f};
#pragma unroll
  for (int sg = 0; sg < 16; ++sg) {
    float4 p = ((const float4*)part)[(b * 16 + sg) * 256 + tid];
    acc.x += p.x;
    acc.y += p.y;
    acc.z += p.z;
    acc.w += p.w;
  }
  ((float4*)ctx)[b * 256 + tid] = acc;
}

// ---------------------------------------------------------------------------
extern "C" void kernel_launch(void* const* d_in, const int* in_sizes, int n_in,
                              void* d_out, int out_size, void* d_ws, size_t ws_size,
                              hipStream_t stream) {
  const float* dh = (const float*)d_in[0];
  const float* enc = (const float*)d_in[1];
  const int* mask = (const int*)d_in[2];
  const float* attn_W = (const float*)d_in[3];
  const float* attn_b = (const float*)d_in[4];
  const float* v_w = (const float*)d_in[5];

  float* out_w = (float*)d_out;                   // [32][2048]
  float* out_ctx = (float*)d_out + NROWS;         // [32][1024]

  // ws layout (floats). part aliases decpart: decpart's lifetime
  // (k_dec_part -> k_dec_reduce) ends before k_energy writes part.
  float* ws = (float*)d_ws;
  float* part = ws;                               // 8 * 65536 = 524288
  float* decpart = ws;                            // 16*32*1024 = 524288 (alias)
  float* dec_proj = ws + 8 * NROWS;               // 32768
  unsigned short* WT = (unsigned short*)(dec_proj + BATCH * HIDDEN);  // 1Mi bf16
  float* ctxpart = dec_proj + BATCH * HIDDEN + (HIDDEN * HIDDEN / 2); // 524288

  k_wt<<<dim3(16, 16), 256, 0, stream>>>(attn_W, WT);
  k_dec_part<<<dim3(16, 16), 256, 0, stream>>>(dh, attn_W, decpart);
  k_dec_reduce<<<dim3(128), 256, 0, stream>>>(decpart, attn_b, dec_proj);
  k_energy_mfma<<<dim3(2048), 1024, 0, stream>>>(enc, WT, dec_proj, v_w, part);
  k_softmax<<<dim3(BATCH), 256, 0, stream>>>(part, mask, out_w);
  k_ctx_partial<<<dim3(BATCH, 16), 256, 0, stream>>>(out_w, enc, ctxpart);
  k_ctx_reduce<<<dim3(BATCH), 256, 0, stream>>>(ctxpart, out_ctx);
}